// Round 1
// baseline (588.425 us; speedup 1.0000x reference)
//
#include <hip/hip_runtime.h>
#include <hip/hip_bf16.h>

constexpr int Bn = 64;
constexpr int Ln = 2048;
constexpr int Dn = 128;
constexpr int Hn = 4;
constexpr int An = 128;
constexpr int Mn = 16;
constexpr int Vn = 100000;
constexpr int HDn = 32;
constexpr float GAMMA = 0.3f;
constexpr float BETA = 1.0f;

// workspace layout (in floats); all offsets are multiples of 4 -> 16B aligned
constexpr size_t OFF_PHIP  = 0;                     // 16*128   = 2048
constexpr size_t OFF_SIZEP = 2048;                  // 16
constexpr size_t OFF_PHIQ  = 2064;                  // 64*128   = 8192
constexpr size_t OFF_SUMPS = 10256;                 // 64*16    = 1024
constexpr size_t OFF_C     = 11280;                 // 64*4*128 = 32768
constexpr size_t OFF_PT    = 44048;                 // V*16     = 1600000
constexpr size_t WS_FLOATS_NEEDED = OFF_PT + (size_t)Vn * 16;

// ---------------------------------------------------------------------------
// K1: PhiP[m,a] = sum_v sigmoid(phi[m,v]) * E[v,a]; also writes pT[v,m]
// block: 256 thr; each chunk = 64 v-rows. thread t owns (a = t&127, mg = t>>7)
// fill stage: thread t computes sigmoid for v = t>>2, m = 4*(t&3)+j
// ---------------------------------------------------------------------------
__global__ __launch_bounds__(256) void k_phip(const float* __restrict__ phi,
                                              const float* __restrict__ E,
                                              float* __restrict__ PhiP,
                                              float* __restrict__ pT,
                                              int write_pT) {
    __shared__ float pv[64 * 16];   // pv[v*16 + m]
    const int t = threadIdx.x;
    const int a = t & 127;
    const int mg = t >> 7;          // 0/1 -> m in [mg*8, mg*8+8)
    const int vloc = t >> 2;        // 0..63
    const int mbase = 4 * (t & 3);  // 0,4,8,12

    float acc[8];
#pragma unroll
    for (int k = 0; k < 8; ++k) acc[k] = 0.f;

    for (int v0 = blockIdx.x * 64; v0 < Vn; v0 += gridDim.x * 64) {
        __syncthreads();  // protect pv reuse across chunks
        const int v = v0 + vloc;
        float4 pj = make_float4(0.f, 0.f, 0.f, 0.f);
        if (v < Vn) {
            const float x0 = phi[(size_t)(mbase + 0) * Vn + v];
            const float x1 = phi[(size_t)(mbase + 1) * Vn + v];
            const float x2 = phi[(size_t)(mbase + 2) * Vn + v];
            const float x3 = phi[(size_t)(mbase + 3) * Vn + v];
            pj.x = 1.f / (1.f + __expf(-x0));
            pj.y = 1.f / (1.f + __expf(-x1));
            pj.z = 1.f / (1.f + __expf(-x2));
            pj.w = 1.f / (1.f + __expf(-x3));
        }
        *(float4*)&pv[4 * t] = pj;                       // contiguous, no bank conflict
        if (write_pT && v < Vn) {
            *(float4*)&pT[(size_t)v * 16 + mbase] = pj;  // coalesced: addr = v0*16 + 4t
        }
        __syncthreads();
        const int vmax = min(64, Vn - v0);
#pragma unroll 4
        for (int vv = 0; vv < vmax; ++vv) {
            const float e = E[(size_t)(v0 + vv) * An + a];          // coalesced across 128 lanes
            const float4 p0 = *(const float4*)&pv[vv * 16 + mg * 8];      // broadcast
            const float4 p1 = *(const float4*)&pv[vv * 16 + mg * 8 + 4];  // broadcast
            acc[0] += p0.x * e; acc[1] += p0.y * e; acc[2] += p0.z * e; acc[3] += p0.w * e;
            acc[4] += p1.x * e; acc[5] += p1.y * e; acc[6] += p1.z * e; acc[7] += p1.w * e;
        }
    }
#pragma unroll
    for (int k = 0; k < 8; ++k)
        atomicAdd(&PhiP[(size_t)(mg * 8 + k) * An + a], acc[k]);
}

// ---------------------------------------------------------------------------
// K1b: sizeP[m] = sum_v sigmoid(phi[m,v])  (deterministic per-m reduction)
// ---------------------------------------------------------------------------
__global__ __launch_bounds__(256) void k_sizep(const float* __restrict__ phi,
                                               float* __restrict__ sizeP) {
    const int m = blockIdx.x;
    const int t = threadIdx.x;
    float s = 0.f;
    for (int v = t; v < Vn; v += 256)
        s += 1.f / (1.f + __expf(-phi[(size_t)m * Vn + v]));
#pragma unroll
    for (int off = 32; off > 0; off >>= 1) s += __shfl_down(s, off);
    __shared__ float red[4];
    if ((t & 63) == 0) red[t >> 6] = s;
    __syncthreads();
    if (t == 0) sizeP[m] = red[0] + red[1] + red[2] + red[3];
}

// ---------------------------------------------------------------------------
// K2: PhiQ[b,a] = sum_{i in seg b} E[qid[i],a];  sumpS[b,m] = sum_i pT[qid[i],m]
// grid (16 splits, B). block 256.
// ---------------------------------------------------------------------------
__global__ __launch_bounds__(256) void k_phiq(const int* __restrict__ qid,
                                              const int* __restrict__ offs,
                                              const float* __restrict__ E,
                                              const float* __restrict__ phi,
                                              const float* __restrict__ pT,
                                              int usepT,
                                              float* __restrict__ PhiQ,
                                              float* __restrict__ sumpS) {
    const int b = blockIdx.y;
    const int s0 = offs[b], s1 = offs[b + 1];
    const int len = s1 - s0;
    const int chunk = (len + (int)gridDim.x - 1) / (int)gridDim.x;
    const int start = s0 + (int)blockIdx.x * chunk;
    const int end = min(start + chunk, s1);
    const int t = threadIdx.x;

    // --- PhiQ: 8 entries in flight; thread covers float4 column a4 of its entry
    {
        const int a4 = t & 31, sub = t >> 5;
        float4 acc = make_float4(0.f, 0.f, 0.f, 0.f);
        const float4* E4 = (const float4*)E;
        for (int i = start + sub; i < end; i += 8) {
            const float4 e = E4[(size_t)qid[i] * 32 + a4];
            acc.x += e.x; acc.y += e.y; acc.z += e.z; acc.w += e.w;
        }
        float* dst = &PhiQ[(size_t)b * An + a4 * 4];
        atomicAdd(dst + 0, acc.x);
        atomicAdd(dst + 1, acc.y);
        atomicAdd(dst + 2, acc.z);
        atomicAdd(dst + 3, acc.w);
    }

    // --- sumpS
    __shared__ float sP[Mn];
    if (t < Mn) sP[t] = 0.f;
    __syncthreads();
    if (usepT) {
        const int m4 = t & 3, io = t >> 2;   // 64 entries in flight, 4 lanes/entry
        float4 acc = make_float4(0.f, 0.f, 0.f, 0.f);
        const float4* pT4 = (const float4*)pT;
        for (int i = start + io; i < end; i += 64) {
            const float4 p = pT4[(size_t)qid[i] * 4 + m4];  // one 64B line per entry
            acc.x += p.x; acc.y += p.y; acc.z += p.z; acc.w += p.w;
        }
        atomicAdd(&sP[m4 * 4 + 0], acc.x);
        atomicAdd(&sP[m4 * 4 + 1], acc.y);
        atomicAdd(&sP[m4 * 4 + 2], acc.z);
        atomicAdd(&sP[m4 * 4 + 3], acc.w);
    } else {
        const int m = t & 15, io = t >> 4;
        float accp = 0.f;
        for (int i = start + io; i < end; i += 16) {
            const float x = phi[(size_t)m * Vn + qid[i]];
            accp += 1.f / (1.f + __expf(-x));
        }
        atomicAdd(&sP[m], accp);
    }
    __syncthreads();
    if (t < Mn) atomicAdd(&sumpS[(size_t)b * Mn + t], sP[t]);
}

// ---------------------------------------------------------------------------
// K3: per-b block (128 thr): BP, Vp, AQ, scores, softmax, Z, C[b,h,:]
// ---------------------------------------------------------------------------
__global__ __launch_bounds__(128) void k_small(const float* __restrict__ PhiP,
                                               const float* __restrict__ sizeP,
                                               const float* __restrict__ PhiQ,
                                               const float* __restrict__ sumpS,
                                               const int* __restrict__ offs,
                                               const float* __restrict__ W_A,
                                               const float* __restrict__ W_B,
                                               const float* __restrict__ W_val,
                                               const float* __restrict__ b_val,
                                               const float* __restrict__ W_out,
                                               const float* __restrict__ size_w,
                                               float* __restrict__ Cws) {
    const int b = blockIdx.x;
    const int i = threadIdx.x;
    __shared__ float BP[Mn * An];
    __shared__ float Vp[Mn * HDn];
    __shared__ float AQs[An];
    __shared__ float sc[Mn];
    __shared__ float attn[Mn];
    __shared__ float Zs[HDn];

    // AQ[i] = PhiQ[b,:] . W_A[i,:]
    {
        const float4* wa = (const float4*)(W_A + (size_t)i * An);
        const float4* pq = (const float4*)(PhiQ + (size_t)b * An);
        float aq = 0.f;
        for (int q = 0; q < An / 4; ++q) {
            const float4 w = wa[q], p = pq[q];
            aq += w.x * p.x + w.y * p.y + w.z * p.z + w.w * p.w;
        }
        AQs[i] = aq;
    }
    // BP[m,i] = PhiP[m,:] . W_B[i,:]
    {
        const float4* wb = (const float4*)(W_B + (size_t)i * An);
        for (int m = 0; m < Mn; ++m) {
            const float4* pp = (const float4*)(PhiP + (size_t)m * An);
            float s = 0.f;
            for (int q = 0; q < An / 4; ++q) {
                const float4 w = wb[q], p = pp[q];
                s += w.x * p.x + w.y * p.y + w.z * p.z + w.w * p.w;
            }
            BP[m * An + i] = s;
        }
    }
    // Vp[m,j] = PhiP[m,:] . W_val[j,:] + b_val[j]
    if (i < HDn) {
        const float4* wv = (const float4*)(W_val + (size_t)i * An);
        for (int m = 0; m < Mn; ++m) {
            const float4* pp = (const float4*)(PhiP + (size_t)m * An);
            float s = 0.f;
            for (int q = 0; q < An / 4; ++q) {
                const float4 w = wv[q], p = pp[q];
                s += w.x * p.x + w.y * p.y + w.z * p.z + w.w * p.w;
            }
            Vp[m * HDn + i] = s + b_val[i];
        }
    }
    __syncthreads();

    const float szQ = (float)(offs[b + 1] - offs[b]);
    if (i < Mn) {
        float d = 0.f;
        for (int a = 0; a < An; ++a) d += AQs[a] * BP[i * An + a];
        const float delta = szQ + sizeP[i] - 2.f * sumpS[(size_t)b * Mn + i];
        sc[i] = -GAMMA * delta + BETA * d + size_w[0] * szQ + size_w[1] * sizeP[i];
    }
    __syncthreads();
    if (i < Mn) {
        float mx = sc[0];
        for (int m = 1; m < Mn; ++m) mx = fmaxf(mx, sc[m]);
        float sum = 0.f;
        for (int m = 0; m < Mn; ++m) sum += __expf(sc[m] - mx);
        attn[i] = __expf(sc[i] - mx) / sum;
    }
    __syncthreads();
    if (i < HDn) {
        float z = 0.f;
        for (int m = 0; m < Mn; ++m) z += attn[m] * Vp[m * HDn + i];
        Zs[i] = z;
    }
    __syncthreads();
    {
        const float* wo = W_out + (size_t)i * Dn;
#pragma unroll
        for (int h = 0; h < Hn; ++h) {
            float c = 0.f;
#pragma unroll
            for (int j = 0; j < HDn; ++j) c += Zs[j] * wo[h * HDn + j];
            Cws[((size_t)b * Hn + h) * Dn + i] = c;
        }
    }
}

// ---------------------------------------------------------------------------
// K4: out[b,l,:] = b_out + sum_h softmax_h(ts[b,l,:].W_gate[h]+b_gate) * C[b,h,:]
// 2 tokens per wave (32 lanes each), float4 everywhere.
// ---------------------------------------------------------------------------
__global__ __launch_bounds__(256) void k_out(const float* __restrict__ ts,
                                             const float* __restrict__ W_gate,
                                             const float* __restrict__ b_gate,
                                             const float* __restrict__ b_out,
                                             const float* __restrict__ Cws,
                                             float* __restrict__ out) {
    constexpr int CHUNK = 128;
    const int b = blockIdx.y;
    const int t = threadIdx.x;
    __shared__ float4 WgS[Hn * 32];
    __shared__ float4 CS[Hn * 32];
    __shared__ float4 boS[32];
    __shared__ float bgS[Hn];
    if (t < 128) WgS[t] = ((const float4*)W_gate)[t];
    else CS[t - 128] = ((const float4*)(Cws + (size_t)b * Hn * Dn))[t - 128];
    if (t < 32) boS[t] = ((const float4*)b_out)[t];
    if (t >= 64 && t < 64 + Hn) bgS[t - 64] = b_gate[t - 64];
    __syncthreads();

    const int sl = t & 31;   // lane within 32-group: float4 column
    const int tg = t >> 5;   // 0..7 token sub-slot per iteration
    const size_t rowbase = (size_t)b * Ln + (size_t)blockIdx.x * CHUNK;
    const float4* x4 = (const float4*)ts + rowbase * 32;
    float4* o4 = (float4*)out + rowbase * 32;

    const float4 w0 = WgS[0 * 32 + sl], w1 = WgS[1 * 32 + sl];
    const float4 w2 = WgS[2 * 32 + sl], w3 = WgS[3 * 32 + sl];
    const float4 c0 = CS[0 * 32 + sl], c1 = CS[1 * 32 + sl];
    const float4 c2 = CS[2 * 32 + sl], c3 = CS[3 * 32 + sl];
    const float4 bo = boS[sl];
    const float bg0 = bgS[0], bg1 = bgS[1], bg2 = bgS[2], bg3 = bgS[3];

    for (int it = 0; it < CHUNK / 8; ++it) {
        const int tok = it * 8 + tg;
        const float4 x = x4[(size_t)tok * 32 + sl];
        float a0 = x.x * w0.x + x.y * w0.y + x.z * w0.z + x.w * w0.w;
        float a1 = x.x * w1.x + x.y * w1.y + x.z * w1.z + x.w * w1.w;
        float a2 = x.x * w2.x + x.y * w2.y + x.z * w2.z + x.w * w2.w;
        float a3 = x.x * w3.x + x.y * w3.y + x.z * w3.z + x.w * w3.w;
#pragma unroll
        for (int off = 16; off > 0; off >>= 1) {   // reduce within 32-lane half-wave
            a0 += __shfl_xor(a0, off);
            a1 += __shfl_xor(a1, off);
            a2 += __shfl_xor(a2, off);
            a3 += __shfl_xor(a3, off);
        }
        a0 += bg0; a1 += bg1; a2 += bg2; a3 += bg3;
        const float mx = fmaxf(fmaxf(a0, a1), fmaxf(a2, a3));
        const float e0 = __expf(a0 - mx), e1 = __expf(a1 - mx);
        const float e2 = __expf(a2 - mx), e3 = __expf(a3 - mx);
        const float inv = 1.f / (e0 + e1 + e2 + e3);
        const float g0 = e0 * inv, g1 = e1 * inv, g2 = e2 * inv, g3 = e3 * inv;
        float4 o = bo;
        o.x += g0 * c0.x + g1 * c1.x + g2 * c2.x + g3 * c3.x;
        o.y += g0 * c0.y + g1 * c1.y + g2 * c2.y + g3 * c3.y;
        o.z += g0 * c0.z + g1 * c1.z + g2 * c2.z + g3 * c3.z;
        o.w += g0 * c0.w + g1 * c1.w + g2 * c2.w + g3 * c3.w;
        o4[(size_t)tok * 32 + sl] = o;
    }
}

extern "C" void kernel_launch(void* const* d_in, const int* in_sizes, int n_in,
                              void* d_out, int out_size, void* d_ws, size_t ws_size,
                              hipStream_t stream) {
    const float* ts     = (const float*)d_in[0];
    const int*   qid    = (const int*)d_in[1];
    const int*   offs   = (const int*)d_in[2];
    const float* E      = (const float*)d_in[3];
    const float* phi    = (const float*)d_in[4];
    const float* W_A    = (const float*)d_in[5];
    const float* W_B    = (const float*)d_in[6];
    const float* W_val  = (const float*)d_in[7];
    const float* b_val  = (const float*)d_in[8];
    const float* W_gate = (const float*)d_in[9];
    const float* b_gate = (const float*)d_in[10];
    const float* W_out  = (const float*)d_in[11];
    const float* b_out  = (const float*)d_in[12];
    const float* size_w = (const float*)d_in[13];
    float* out = (float*)d_out;
    float* ws  = (float*)d_ws;

    float* PhiP  = ws + OFF_PHIP;
    float* sizeP = ws + OFF_SIZEP;
    float* PhiQ  = ws + OFF_PHIQ;
    float* sumpS = ws + OFF_SUMPS;
    float* Cws   = ws + OFF_C;
    float* pT    = ws + OFF_PT;
    const int usepT = (ws_size >= WS_FLOATS_NEEDED * sizeof(float)) ? 1 : 0;

    hipMemsetAsync(ws, 0, OFF_C * sizeof(float), stream);  // zero accumulators
    k_phip<<<dim3(256), dim3(256), 0, stream>>>(phi, E, PhiP, pT, usepT);
    k_sizep<<<dim3(Mn), dim3(256), 0, stream>>>(phi, sizeP);
    k_phiq<<<dim3(16, Bn), dim3(256), 0, stream>>>(qid, offs, E, phi, pT, usepT, PhiQ, sumpS);
    k_small<<<dim3(Bn), dim3(128), 0, stream>>>(PhiP, sizeP, PhiQ, sumpS, offs,
                                                W_A, W_B, W_val, b_val, W_out, size_w, Cws);
    k_out<<<dim3(Ln / 128, Bn), dim3(256), 0, stream>>>(ts, W_gate, b_gate, b_out, Cws, out);
}

// Round 2
// 322.377 us; speedup vs baseline: 1.8253x; 1.8253x over previous
//
#include <hip/hip_runtime.h>
#include <hip/hip_bf16.h>

constexpr int Bn = 64;
constexpr int Ln = 2048;
constexpr int Dn = 128;
constexpr int Hn = 4;
constexpr int An = 128;
constexpr int Mn = 16;
constexpr int Vn = 100000;
constexpr int HDn = 32;
constexpr float GAMMA = 0.3f;
constexpr float BETA = 1.0f;

// workspace layout (in floats); all offsets are multiples of 4 -> 16B aligned
constexpr size_t OFF_PHIP  = 0;                     // 16*128   = 2048
constexpr size_t OFF_SIZEP = 2048;                  // 16
constexpr size_t OFF_PHIQ  = 2064;                  // 64*128   = 8192
constexpr size_t OFF_SUMPS = 10256;                 // 64*16    = 1024
constexpr size_t OFF_C     = 11280;                 // 64*4*128 = 32768
constexpr size_t OFF_PT    = 44048;                 // V*16     = 1600000
constexpr size_t WS_FLOATS_NEEDED = OFF_PT + (size_t)Vn * 16;

// ---------------------------------------------------------------------------
// K1: PhiP[m,a] = sum_v sigmoid(phi[m,v]) * E[v,a]; writes pT[v,m]; sizeP[m].
// block 256. fill: thread t computes sigmoid for v=t>>2, m=4*(t&3)+j.
// compute: a4 = t&31 (float4 col), g = t>>5 -> m in {2g, 2g+1}.
// ---------------------------------------------------------------------------
__global__ __launch_bounds__(256) void k_phip(const float* __restrict__ phi,
                                              const float* __restrict__ E,
                                              float* __restrict__ PhiP,
                                              float* __restrict__ sizeP,
                                              float* __restrict__ pT,
                                              int write_pT) {
    __shared__ float pv[64 * 16];   // pv[v*16 + m]
    __shared__ float szl[Mn];
    const int t = threadIdx.x;
    const int a4 = t & 31;
    const int g = t >> 5;           // 0..7 -> m = 2g, 2g+1
    const int vloc = t >> 2;        // 0..63
    const int mbase = 4 * (t & 3);  // 0,4,8,12

    if (t < Mn) szl[t] = 0.f;

    float4 acc0 = make_float4(0.f, 0.f, 0.f, 0.f);
    float4 acc1 = make_float4(0.f, 0.f, 0.f, 0.f);
    float4 szacc = make_float4(0.f, 0.f, 0.f, 0.f);

    for (int v0 = blockIdx.x * 64; v0 < Vn; v0 += gridDim.x * 64) {
        __syncthreads();  // protect pv reuse across chunks (also covers szl init)
        const int v = v0 + vloc;
        float4 pj = make_float4(0.f, 0.f, 0.f, 0.f);
        if (v < Vn) {
            const float x0 = phi[(size_t)(mbase + 0) * Vn + v];
            const float x1 = phi[(size_t)(mbase + 1) * Vn + v];
            const float x2 = phi[(size_t)(mbase + 2) * Vn + v];
            const float x3 = phi[(size_t)(mbase + 3) * Vn + v];
            pj.x = 1.f / (1.f + __expf(-x0));
            pj.y = 1.f / (1.f + __expf(-x1));
            pj.z = 1.f / (1.f + __expf(-x2));
            pj.w = 1.f / (1.f + __expf(-x3));
        }
        *(float4*)&pv[4 * t] = pj;
        szacc.x += pj.x; szacc.y += pj.y; szacc.z += pj.z; szacc.w += pj.w;
        if (write_pT && v < Vn) {
            *(float4*)&pT[(size_t)v * 16 + mbase] = pj;  // coalesced
        }
        __syncthreads();
        const int vmax = min(64, Vn - v0);
#pragma unroll 8
        for (int vv = 0; vv < vmax; ++vv) {
            const float4 e = *(const float4*)&E[(size_t)(v0 + vv) * An + a4 * 4];
            const float2 pm = *(const float2*)&pv[vv * 16 + g * 2];  // broadcast
            acc0.x += pm.x * e.x; acc0.y += pm.x * e.y; acc0.z += pm.x * e.z; acc0.w += pm.x * e.w;
            acc1.x += pm.y * e.x; acc1.y += pm.y * e.y; acc1.z += pm.y * e.z; acc1.w += pm.y * e.w;
        }
    }
    // PhiP: unique owner per element per block -> direct global atomics
    {
        float* d0 = &PhiP[(size_t)(2 * g + 0) * An + a4 * 4];
        float* d1 = &PhiP[(size_t)(2 * g + 1) * An + a4 * 4];
        atomicAdd(d0 + 0, acc0.x); atomicAdd(d0 + 1, acc0.y);
        atomicAdd(d0 + 2, acc0.z); atomicAdd(d0 + 3, acc0.w);
        atomicAdd(d1 + 0, acc1.x); atomicAdd(d1 + 1, acc1.y);
        atomicAdd(d1 + 2, acc1.z); atomicAdd(d1 + 3, acc1.w);
    }
    // sizeP: LDS reduce then 16 global atomics per block
    atomicAdd(&szl[mbase + 0], szacc.x);
    atomicAdd(&szl[mbase + 1], szacc.y);
    atomicAdd(&szl[mbase + 2], szacc.z);
    atomicAdd(&szl[mbase + 3], szacc.w);
    __syncthreads();
    if (t < Mn) atomicAdd(&sizeP[t], szl[t]);
}

// ---------------------------------------------------------------------------
// K2: PhiQ[b,a] = sum_{i in seg b} E[qid[i],a];  sumpS[b,m] = sum_i pT[qid[i],m]
// grid (64 splits, B). block 256. Unroll-by-4 index prefetch, LDS staging.
// ---------------------------------------------------------------------------
__global__ __launch_bounds__(256) void k_phiq(const int* __restrict__ qid,
                                              const int* __restrict__ offs,
                                              const float* __restrict__ E,
                                              const float* __restrict__ phi,
                                              const float* __restrict__ pT,
                                              int usepT,
                                              float* __restrict__ PhiQ,
                                              float* __restrict__ sumpS) {
    const int b = blockIdx.y;
    const int s0 = offs[b], s1 = offs[b + 1];
    const int len = s1 - s0;
    const int nsplit = (int)gridDim.x;
    const int chunk = (len + nsplit - 1) / nsplit;
    const int start = s0 + (int)blockIdx.x * chunk;
    const int end = min(start + chunk, s1);
    const int t = threadIdx.x;

    __shared__ float phl[8 * 128];
    __shared__ float sP[Mn];
    if (t < Mn) sP[t] = 0.f;

    // --- Phase 1: PhiQ. 8 entries in flight (32 lanes/entry), unroll 4.
    {
        const int a4 = t & 31, sub = t >> 5;
        float4 acc = make_float4(0.f, 0.f, 0.f, 0.f);
        const float4* E4 = (const float4*)E;
        int i = start + sub;
        for (; i + 24 < end; i += 32) {
            const int q0 = qid[i], q1 = qid[i + 8], q2 = qid[i + 16], q3 = qid[i + 24];
            const float4 e0 = E4[(size_t)q0 * 32 + a4];
            const float4 e1 = E4[(size_t)q1 * 32 + a4];
            const float4 e2 = E4[(size_t)q2 * 32 + a4];
            const float4 e3 = E4[(size_t)q3 * 32 + a4];
            acc.x += e0.x + e1.x + e2.x + e3.x;
            acc.y += e0.y + e1.y + e2.y + e3.y;
            acc.z += e0.z + e1.z + e2.z + e3.z;
            acc.w += e0.w + e1.w + e2.w + e3.w;
        }
        for (; i < end; i += 8) {
            const float4 e = E4[(size_t)qid[i] * 32 + a4];
            acc.x += e.x; acc.y += e.y; acc.z += e.z; acc.w += e.w;
        }
        *(float4*)&phl[sub * 128 + a4 * 4] = acc;
    }
    __syncthreads();
    if (t < 128) {
        float s = 0.f;
#pragma unroll
        for (int k = 0; k < 8; ++k) s += phl[k * 128 + t];
        atomicAdd(&PhiQ[(size_t)b * An + t], s);
    }

    // --- Phase 2: sumpS. 64 entries in flight (4 lanes/entry), unroll 4.
    float4 acc = make_float4(0.f, 0.f, 0.f, 0.f);
    const int m4 = t & 3, io = t >> 2;
    if (usepT) {
        const float4* pT4 = (const float4*)pT;
        int i = start + io;
        for (; i + 192 < end; i += 256) {
            const int q0 = qid[i], q1 = qid[i + 64], q2 = qid[i + 128], q3 = qid[i + 192];
            const float4 p0 = pT4[(size_t)q0 * 4 + m4];
            const float4 p1 = pT4[(size_t)q1 * 4 + m4];
            const float4 p2 = pT4[(size_t)q2 * 4 + m4];
            const float4 p3 = pT4[(size_t)q3 * 4 + m4];
            acc.x += p0.x + p1.x + p2.x + p3.x;
            acc.y += p0.y + p1.y + p2.y + p3.y;
            acc.z += p0.z + p1.z + p2.z + p3.z;
            acc.w += p0.w + p1.w + p2.w + p3.w;
        }
        for (; i < end; i += 64) {
            const float4 p = pT4[(size_t)qid[i] * 4 + m4];
            acc.x += p.x; acc.y += p.y; acc.z += p.z; acc.w += p.w;
        }
    } else {
        for (int i = start + io; i < end; i += 64) {
            const int q = qid[i];
            acc.x += 1.f / (1.f + __expf(-phi[(size_t)(m4 * 4 + 0) * Vn + q]));
            acc.y += 1.f / (1.f + __expf(-phi[(size_t)(m4 * 4 + 1) * Vn + q]));
            acc.z += 1.f / (1.f + __expf(-phi[(size_t)(m4 * 4 + 2) * Vn + q]));
            acc.w += 1.f / (1.f + __expf(-phi[(size_t)(m4 * 4 + 3) * Vn + q]));
        }
    }
    // wave-level butterfly over the 16 lanes sharing m4 (xor bits 2..5)
#pragma unroll
    for (int off = 32; off >= 4; off >>= 1) {
        acc.x += __shfl_xor(acc.x, off);
        acc.y += __shfl_xor(acc.y, off);
        acc.z += __shfl_xor(acc.z, off);
        acc.w += __shfl_xor(acc.w, off);
    }
    if ((t & 63) < 4) {
        atomicAdd(&sP[m4 * 4 + 0], acc.x);
        atomicAdd(&sP[m4 * 4 + 1], acc.y);
        atomicAdd(&sP[m4 * 4 + 2], acc.z);
        atomicAdd(&sP[m4 * 4 + 3], acc.w);
    }
    __syncthreads();
    if (t < Mn) atomicAdd(&sumpS[(size_t)b * Mn + t], sP[t]);
}

// ---------------------------------------------------------------------------
// K3: per-b block (128 thr): BP, Vp, AQ, scores, softmax, Z, C[b,h,:]
// ---------------------------------------------------------------------------
__global__ __launch_bounds__(128) void k_small(const float* __restrict__ PhiP,
                                               const float* __restrict__ sizeP,
                                               const float* __restrict__ PhiQ,
                                               const float* __restrict__ sumpS,
                                               const int* __restrict__ offs,
                                               const float* __restrict__ W_A,
                                               const float* __restrict__ W_B,
                                               const float* __restrict__ W_val,
                                               const float* __restrict__ b_val,
                                               const float* __restrict__ W_out,
                                               const float* __restrict__ size_w,
                                               float* __restrict__ Cws) {
    const int b = blockIdx.x;
    const int i = threadIdx.x;
    __shared__ float BP[Mn * An];
    __shared__ float Vp[Mn * HDn];
    __shared__ float AQs[An];
    __shared__ float sc[Mn];
    __shared__ float attn[Mn];
    __shared__ float Zs[HDn];

    {
        const float4* wa = (const float4*)(W_A + (size_t)i * An);
        const float4* pq = (const float4*)(PhiQ + (size_t)b * An);
        float aq = 0.f;
        for (int q = 0; q < An / 4; ++q) {
            const float4 w = wa[q], p = pq[q];
            aq += w.x * p.x + w.y * p.y + w.z * p.z + w.w * p.w;
        }
        AQs[i] = aq;
    }
    {
        const float4* wb = (const float4*)(W_B + (size_t)i * An);
        for (int m = 0; m < Mn; ++m) {
            const float4* pp = (const float4*)(PhiP + (size_t)m * An);
            float s = 0.f;
            for (int q = 0; q < An / 4; ++q) {
                const float4 w = wb[q], p = pp[q];
                s += w.x * p.x + w.y * p.y + w.z * p.z + w.w * p.w;
            }
            BP[m * An + i] = s;
        }
    }
    if (i < HDn) {
        const float4* wv = (const float4*)(W_val + (size_t)i * An);
        for (int m = 0; m < Mn; ++m) {
            const float4* pp = (const float4*)(PhiP + (size_t)m * An);
            float s = 0.f;
            for (int q = 0; q < An / 4; ++q) {
                const float4 w = wv[q], p = pp[q];
                s += w.x * p.x + w.y * p.y + w.z * p.z + w.w * p.w;
            }
            Vp[m * HDn + i] = s + b_val[i];
        }
    }
    __syncthreads();

    const float szQ = (float)(offs[b + 1] - offs[b]);
    if (i < Mn) {
        float d = 0.f;
        for (int a = 0; a < An; ++a) d += AQs[a] * BP[i * An + a];
        const float delta = szQ + sizeP[i] - 2.f * sumpS[(size_t)b * Mn + i];
        sc[i] = -GAMMA * delta + BETA * d + size_w[0] * szQ + size_w[1] * sizeP[i];
    }
    __syncthreads();
    if (i < Mn) {
        float mx = sc[0];
        for (int m = 1; m < Mn; ++m) mx = fmaxf(mx, sc[m]);
        float sum = 0.f;
        for (int m = 0; m < Mn; ++m) sum += __expf(sc[m] - mx);
        attn[i] = __expf(sc[i] - mx) / sum;
    }
    __syncthreads();
    if (i < HDn) {
        float z = 0.f;
        for (int m = 0; m < Mn; ++m) z += attn[m] * Vp[m * HDn + i];
        Zs[i] = z;
    }
    __syncthreads();
    {
        const float* wo = W_out + (size_t)i * Dn;
#pragma unroll
        for (int h = 0; h < Hn; ++h) {
            float c = 0.f;
#pragma unroll
            for (int j = 0; j < HDn; ++j) c += Zs[j] * wo[h * HDn + j];
            Cws[((size_t)b * Hn + h) * Dn + i] = c;
        }
    }
}

// ---------------------------------------------------------------------------
// K4: out[b,l,:] = b_out + sum_h softmax_h(ts[b,l,:].W_gate[h]+b_gate) * C[b,h,:]
// ---------------------------------------------------------------------------
__global__ __launch_bounds__(256) void k_out(const float* __restrict__ ts,
                                             const float* __restrict__ W_gate,
                                             const float* __restrict__ b_gate,
                                             const float* __restrict__ b_out,
                                             const float* __restrict__ Cws,
                                             float* __restrict__ out) {
    constexpr int CHUNK = 128;
    const int b = blockIdx.y;
    const int t = threadIdx.x;
    __shared__ float4 WgS[Hn * 32];
    __shared__ float4 CS[Hn * 32];
    __shared__ float4 boS[32];
    __shared__ float bgS[Hn];
    if (t < 128) WgS[t] = ((const float4*)W_gate)[t];
    else CS[t - 128] = ((const float4*)(Cws + (size_t)b * Hn * Dn))[t - 128];
    if (t < 32) boS[t] = ((const float4*)b_out)[t];
    if (t >= 64 && t < 64 + Hn) bgS[t - 64] = b_gate[t - 64];
    __syncthreads();

    const int sl = t & 31;
    const int tg = t >> 5;
    const size_t rowbase = (size_t)b * Ln + (size_t)blockIdx.x * CHUNK;
    const float4* x4 = (const float4*)ts + rowbase * 32;
    float4* o4 = (float4*)out + rowbase * 32;

    const float4 w0 = WgS[0 * 32 + sl], w1 = WgS[1 * 32 + sl];
    const float4 w2 = WgS[2 * 32 + sl], w3 = WgS[3 * 32 + sl];
    const float4 c0 = CS[0 * 32 + sl], c1 = CS[1 * 32 + sl];
    const float4 c2 = CS[2 * 32 + sl], c3 = CS[3 * 32 + sl];
    const float4 bo = boS[sl];
    const float bg0 = bgS[0], bg1 = bgS[1], bg2 = bgS[2], bg3 = bgS[3];

    for (int it = 0; it < CHUNK / 8; ++it) {
        const int tok = it * 8 + tg;
        const float4 x = x4[(size_t)tok * 32 + sl];
        float a0 = x.x * w0.x + x.y * w0.y + x.z * w0.z + x.w * w0.w;
        float a1 = x.x * w1.x + x.y * w1.y + x.z * w1.z + x.w * w1.w;
        float a2 = x.x * w2.x + x.y * w2.y + x.z * w2.z + x.w * w2.w;
        float a3 = x.x * w3.x + x.y * w3.y + x.z * w3.z + x.w * w3.w;
#pragma unroll
        for (int off = 16; off > 0; off >>= 1) {
            a0 += __shfl_xor(a0, off);
            a1 += __shfl_xor(a1, off);
            a2 += __shfl_xor(a2, off);
            a3 += __shfl_xor(a3, off);
        }
        a0 += bg0; a1 += bg1; a2 += bg2; a3 += bg3;
        const float mx = fmaxf(fmaxf(a0, a1), fmaxf(a2, a3));
        const float e0 = __expf(a0 - mx), e1 = __expf(a1 - mx);
        const float e2 = __expf(a2 - mx), e3 = __expf(a3 - mx);
        const float inv = 1.f / (e0 + e1 + e2 + e3);
        const float g0 = e0 * inv, g1 = e1 * inv, g2 = e2 * inv, g3 = e3 * inv;
        float4 o = bo;
        o.x += g0 * c0.x + g1 * c1.x + g2 * c2.x + g3 * c3.x;
        o.y += g0 * c0.y + g1 * c1.y + g2 * c2.y + g3 * c3.y;
        o.z += g0 * c0.z + g1 * c1.z + g2 * c2.z + g3 * c3.z;
        o.w += g0 * c0.w + g1 * c1.w + g2 * c2.w + g3 * c3.w;
        o4[(size_t)tok * 32 + sl] = o;
    }
}

extern "C" void kernel_launch(void* const* d_in, const int* in_sizes, int n_in,
                              void* d_out, int out_size, void* d_ws, size_t ws_size,
                              hipStream_t stream) {
    const float* ts     = (const float*)d_in[0];
    const int*   qid    = (const int*)d_in[1];
    const int*   offs   = (const int*)d_in[2];
    const float* E      = (const float*)d_in[3];
    const float* phi    = (const float*)d_in[4];
    const float* W_A    = (const float*)d_in[5];
    const float* W_B    = (const float*)d_in[6];
    const float* W_val  = (const float*)d_in[7];
    const float* b_val  = (const float*)d_in[8];
    const float* W_gate = (const float*)d_in[9];
    const float* b_gate = (const float*)d_in[10];
    const float* W_out  = (const float*)d_in[11];
    const float* b_out  = (const float*)d_in[12];
    const float* size_w = (const float*)d_in[13];
    float* out = (float*)d_out;
    float* ws  = (float*)d_ws;

    float* PhiP  = ws + OFF_PHIP;
    float* sizeP = ws + OFF_SIZEP;
    float* PhiQ  = ws + OFF_PHIQ;
    float* sumpS = ws + OFF_SUMPS;
    float* Cws   = ws + OFF_C;
    float* pT    = ws + OFF_PT;
    const int usepT = (ws_size >= WS_FLOATS_NEEDED * sizeof(float)) ? 1 : 0;

    hipMemsetAsync(ws, 0, OFF_C * sizeof(float), stream);  // zero accumulators
    k_phip<<<dim3(512), dim3(256), 0, stream>>>(phi, E, PhiP, sizeP, pT, usepT);
    k_phiq<<<dim3(64, Bn), dim3(256), 0, stream>>>(qid, offs, E, phi, pT, usepT, PhiQ, sumpS);
    k_small<<<dim3(Bn), dim3(128), 0, stream>>>(PhiP, sizeP, PhiQ, sumpS, offs,
                                                W_A, W_B, W_val, b_val, W_out, size_w, Cws);
    k_out<<<dim3(Ln / 128, Bn), dim3(256), 0, stream>>>(ts, W_gate, b_gate, b_out, Cws, out);
}